// Round 15
// baseline (166.844 us; speedup 1.0000x reference)
//
#include <hip/hip_runtime.h>
#include <hip/hip_bf16.h>
#include <math.h>

#define TARLEN 263680
#define POWEXP 2.302585092994046f  // ln(10)
#define S5(k) ((k) + ((k) >> 5))   // spectrum LDS padding (1 per 32)

typedef __attribute__((ext_vector_type(8))) short bf16x8;
typedef __attribute__((ext_vector_type(8))) ushort u16x8;
typedef __attribute__((ext_vector_type(4))) float f32x4;
typedef __attribute__((ext_vector_type(2))) float pf2;

__device__ __forceinline__ void gload16(const void* g, void* l) {
    __builtin_amdgcn_global_load_lds((const __attribute__((address_space(1))) void*)g,
                                     (__attribute__((address_space(3))) void*)l, 16, 0, 0);
}

__device__ __forceinline__ float bf16f(ushort u) {
    union { uint u; float f; } v; v.u = (uint)u << 16; return v.f;
}
__device__ __forceinline__ ushort fbf16(float x) {
    __hip_bfloat16 h = __float2bfloat16(x);
    return *reinterpret_cast<ushort*>(&h);
}

// sin/cos in REVOLUTIONS (native v_sin_f32 domain); args are exact binary
// fractions in [0,1) -> no rounding, no range reduction.
__device__ __forceinline__ float vsin_rev(float rev) {
    float r; asm("v_sin_f32 %0, %1" : "=v"(r) : "v"(rev)); return r;
}
__device__ __forceinline__ float vcos_rev(float rev) {
    float r; asm("v_cos_f32 %0, %1" : "=v"(r) : "v"(rev)); return r;
}

// complex mul by (c + i s) on packed float2
__device__ __forceinline__ pf2 cmulp(pf2 a, float c, float s) {
    return a * c + a.yx * (pf2){-s, s};
}

// DPP quad_perm cross-lane (free, VALU-rate). xor1: [1,0,3,2]; xor2: [2,3,0,1]
__device__ __forceinline__ float dppx1(float x) {
    return __int_as_float(__builtin_amdgcn_update_dpp(
        0, __float_as_int(x), 0xB1, 0xF, 0xF, true));
}
__device__ __forceinline__ float dppx2(float x) {
    return __int_as_float(__builtin_amdgcn_update_dpp(
        0, __float_as_int(x), 0x4E, 0xF, 0xF, true));
}

#define WAVE_FENCE() asm volatile("s_waitcnt lgkmcnt(0)" ::: "memory")

// radix-4 butterfly (fwd W4^1=-i; inv +i)
template<bool INV>
__device__ __forceinline__ void bf4(pf2& x0, pf2& x1, pf2& x2, pf2& x3) {
    pf2 a = x0 + x2, b = x0 - x2, cc = x1 + x3, e = x1 - x3;
    pf2 en = INV ? (pf2){-e.y, e.x} : (pf2){e.y, -e.x};
    x0 = a + cc; x2 = a - cc; x1 = b + en; x3 = b - en;
}

__device__ __forceinline__ constexpr int dsw(int k) { return ((k & 3) << 2) | (k >> 2); }

// in-register 16-pt DFT over index a (v[a]) -> result A[k0] stored at v[dsw(k0)].
// All twiddles compile-time constants.
template<bool INV>
__device__ __forceinline__ void dft16(pf2 v[16]) {
#pragma unroll
    for (int a0 = 0; a0 < 4; ++a0)
        bf4<INV>(v[a0], v[4 + a0], v[8 + a0], v[12 + a0]);
    // W16^{a0*q0}: forward (cos, -sin)(2*pi*p/16)
    const float TC[10] = {1.f, 0.92387953f, 0.70710678f, 0.38268343f, 0.f,
                          0.f, -0.70710678f, 0.f, 0.f, -0.92387953f};
    const float TS[10] = {0.f, -0.38268343f, -0.70710678f, -0.92387953f, -1.f,
                          0.f, -0.70710678f, 0.f, 0.f, 0.38268343f};
#pragma unroll
    for (int q0 = 1; q0 < 4; ++q0)
#pragma unroll
        for (int a0 = 1; a0 < 4; ++a0) {
            const int p = a0 * q0;
            float cx = TC[p];
            float sx = INV ? -TS[p] : TS[p];
            v[4 * q0 + a0] = cmulp(v[4 * q0 + a0], cx, sx);
        }
#pragma unroll
    for (int q0 = 0; q0 < 4; ++q0)
        bf4<INV>(v[4 * q0 + 0], v[4 * q0 + 1], v[4 * q0 + 2], v[4 * q0 + 3]);
}

// cross-lane radix-4 over quad lanes (c = lane&3); output k2 mapping rc={0,2,1,3}
template<bool INV>
__device__ __forceinline__ pf2 xl_radix4(pf2 v, int c) {
    pf2 t; t.x = dppx2(v.x); t.y = dppx2(v.y);
    pf2 sum = v + t, dif = t - v;
    pf2 u = (c & 2) ? dif : sum;
    pf2 t2; t2.x = dppx1(u.x); t2.y = dppx1(u.y);
    pf2 res;
    if (c == 0)      res = u + t2;
    else if (c == 1) res = t2 - u;
    else if (c == 2) res = INV ? (pf2){u.x - t2.y, u.y + t2.x}
                               : (pf2){u.x + t2.y, u.y - t2.x};
    else             res = INV ? (pf2){t2.x + u.y, t2.y - u.x}
                               : (pf2){t2.x - u.y, t2.y + u.x};
    return res;
}

// ============ GEMM layer 0 (no norm): 128x128 tile, 512 thr =================
__global__ __launch_bounds__(512) void gemm8(
    const ushort* __restrict__ A, const ushort* __restrict__ Bt,
    const float* __restrict__ bias, ushort* __restrict__ C,
    int K, float* __restrict__ ps, float* __restrict__ pq)
{
    __shared__ ushort As[3][4096];
    __shared__ ushort Bs[3][4096];
    __shared__ float sred[8][2][16];
    __shared__ float qred[8][2][16];
    const int tid = threadIdx.x;
    const int lane = tid & 63;
    const int wid = tid >> 6;
    const int nwg = gridDim.x * gridDim.y;
    const int bid = blockIdx.y * gridDim.x + blockIdx.x;
    const int q8 = nwg >> 3;
    const int swzb = (bid & 7) * q8 + (bid >> 3);
    const int bx = swzb % gridDim.x;
    const int by = swzb / gridDim.x;
    const int m0 = by * 128;
    const int n0 = bx * 128;
    const int NT = K >> 5;

    f32x4 acc[4][2];
#pragma unroll
    for (int m = 0; m < 4; ++m)
#pragma unroll
        for (int n = 0; n < 2; ++n)
            acc[m][n] = (f32x4){0.f, 0.f, 0.f, 0.f};

    const int srow = tid >> 2;
    const int scol = (((tid & 3) ^ ((tid >> 3) & 3)) << 3);

    auto stage = [&](int t, int buf) {
        const int k0 = t << 5;
        gload16(A + (size_t)(m0 + srow) * K + k0 + scol, &As[buf][tid * 8]);
        gload16(Bt + (size_t)(n0 + srow) * K + k0 + scol, &Bs[buf][tid * 8]);
    };

    const int lr = lane & 15;
    const int sw8 = (((lane >> 4) ^ ((lane >> 1) & 3)) << 3);
    const int wm0 = (wid >> 2) * 64;
    const int wn0 = (wid & 3) * 32;

    stage(0, 0);
    stage(1, 1);
    for (int t = 0; t < NT; ++t) {
        const int cur = t % 3;
        if (t + 2 < NT) {
            asm volatile("s_waitcnt vmcnt(2)" ::: "memory");
            __builtin_amdgcn_s_barrier();
            stage(t + 2, (t + 2) % 3);
        } else {
            asm volatile("s_waitcnt vmcnt(0)" ::: "memory");
            __builtin_amdgcn_s_barrier();
        }
        const ushort* as = As[cur];
        const ushort* bs = Bs[cur];
        bf16x8 af[4], bfv[2];
#pragma unroll
        for (int m = 0; m < 4; ++m)
            af[m] = *reinterpret_cast<const bf16x8*>(&as[(wm0 + m * 16 + lr) * 32 + sw8]);
#pragma unroll
        for (int n = 0; n < 2; ++n)
            bfv[n] = *reinterpret_cast<const bf16x8*>(&bs[(wn0 + n * 16 + lr) * 32 + sw8]);
#pragma unroll
        for (int m = 0; m < 4; ++m)
#pragma unroll
            for (int n = 0; n < 2; ++n)
                acc[m][n] = __builtin_amdgcn_mfma_f32_16x16x32_bf16(af[m], bfv[n], acc[m][n], 0, 0, 0);
    }
    __syncthreads();

    const int cr = (lane >> 4) << 2;
    const int cc = lane & 15;
    float sacc[2] = {0.f, 0.f}, qacc[2] = {0.f, 0.f};
#pragma unroll
    for (int m = 0; m < 4; ++m) {
#pragma unroll
        for (int n = 0; n < 2; ++n) {
            int gcol = n0 + wn0 + n * 16 + cc;
            float bv = bias[gcol];
            int grow = m0 + wm0 + m * 16 + cr;
#pragma unroll
            for (int j = 0; j < 4; ++j) {
                float v = acc[m][n][j] + bv;
                sacc[n] += v;
                qacc[n] += v * v;
                C[(size_t)(grow + j) * 512 + gcol] = fbf16(v);
            }
        }
    }
#pragma unroll
    for (int n = 0; n < 2; ++n) {
        float s = sacc[n], q = qacc[n];
        s += __shfl_xor(s, 16); q += __shfl_xor(q, 16);
        s += __shfl_xor(s, 32); q += __shfl_xor(q, 32);
        if (lane < 16) { sred[wid][n][lane] = s; qred[wid][n][lane] = q; }
    }
    __syncthreads();
    if (tid < 128) {
        int wn_ = tid >> 5, n_ = (tid >> 4) & 1, cc_ = tid & 15;
        float s = sred[wn_][n_][cc_] + sred[4 + wn_][n_][cc_];
        float q = qred[wn_][n_][cc_] + qred[4 + wn_][n_][cc_];
        int col = n0 + wn_ * 32 + n_ * 16 + cc_;
        ps[(size_t)by * 512 + col] = s;
        pq[(size_t)by * 512 + col] = q;
    }
}

// ============ GEMM with fused BN (stats reduce + affine + lrelu on A) =======
template<int EPI>
__global__ __launch_bounds__(512) void gemm8n(
    const ushort* __restrict__ H, const ushort* __restrict__ Bt,
    const float* __restrict__ bias,
    const float* __restrict__ psIn, const float* __restrict__ pqIn,
    const float* __restrict__ gamma, const float* __restrict__ beta,
    ushort* __restrict__ C, int K, int Nvalid, int ldc,
    float* __restrict__ psOut, float* __restrict__ pqOut)
{
    __shared__ ushort As[3][4096];
    __shared__ ushort Bs[3][4096];
    __shared__ uint sab[512];
    __shared__ float sred[8][2][16];
    __shared__ float qred[8][2][16];
    const int tid = threadIdx.x;
    const int lane = tid & 63;
    const int wid = tid >> 6;
    const int nwg = gridDim.x * gridDim.y;
    const int bid = blockIdx.y * gridDim.x + blockIdx.x;
    const int q8 = nwg >> 3;
    const int swzb = (bid & 7) * q8 + (bid >> 3);
    const int bx = swzb % gridDim.x;
    const int by = swzb / gridDim.x;
    const int m0 = by * 128;
    const int n0 = bx * 128;
    const int NT = K >> 5;  // even (K=512)

    {
        int c = tid;
        float s = 0.f, q = 0.f;
#pragma unroll 8
        for (int rg = 0; rg < 64; ++rg) { s += psIn[rg * 512 + c]; q += pqIn[rg * 512 + c]; }
        float m = s * (1.f / 8192.f);
        float v = q * (1.f / 8192.f) - m * m;
        float a = rsqrtf(v + 1e-5f) * gamma[c];
        float b = beta[c] - m * a;
        sab[c] = (uint)fbf16(a) | ((uint)fbf16(b) << 16);
    }

    f32x4 acc[4][2];
#pragma unroll
    for (int m = 0; m < 4; ++m)
#pragma unroll
        for (int n = 0; n < 2; ++n)
            acc[m][n] = (f32x4){0.f, 0.f, 0.f, 0.f};

    const int srow = tid >> 2;
    const int scol = (((tid & 3) ^ ((tid >> 3) & 3)) << 3);
    const int lr = lane & 15;
    const int sw8 = (((lane >> 4) ^ ((lane >> 1) & 3)) << 3);
    const int wm0 = (wid >> 2) * 64;
    const int wn0 = (wid & 3) * 32;

    const size_t arow = (size_t)(m0 + srow) * K + scol;
    const size_t brow = (size_t)(n0 + srow) * K + scol;

    auto stageB = [&](int t, int buf) {
        gload16(Bt + brow + (t << 5), &Bs[buf][tid * 8]);
    };
    auto loadA = [&](int t, u16x8& dst) {
        dst = *reinterpret_cast<const u16x8*>(H + arow + (t << 5));
    };

    __syncthreads();  // sab ready

    u16x8 a0, a1;
    stageB(0, 0); loadA(0, a0);
    stageB(1, 1); loadA(1, a1);

    auto iter = [&](int t, u16x8& ar) {
        const int cur = t % 3;
        if (t + 2 < NT) asm volatile("s_waitcnt vmcnt(2)" ::: "memory");
        else            asm volatile("s_waitcnt vmcnt(0)" ::: "memory");
        {
            const uint* pk = &sab[(t << 5) + scol];
            u16x8 o;
#pragma unroll
            for (int j = 0; j < 8; ++j) {
                uint w = pk[j];
                float a = bf16f((ushort)(w & 0xffffu));
                float b = bf16f((ushort)(w >> 16));
                float y = fmaf(bf16f(ar[j]), a, b);
                o[j] = fbf16(y >= 0.f ? y : 0.2f * y);
            }
            *reinterpret_cast<u16x8*>(&As[cur][tid * 8]) = o;
        }
        asm volatile("s_waitcnt lgkmcnt(0)" ::: "memory");
        __builtin_amdgcn_s_barrier();
        if (t + 2 < NT) { stageB(t + 2, (t + 2) % 3); loadA(t + 2, ar); }
        const ushort* as = As[cur];
        const ushort* bs = Bs[cur];
        bf16x8 af[4], bfv[2];
#pragma unroll
        for (int m = 0; m < 4; ++m)
            af[m] = *reinterpret_cast<const bf16x8*>(&as[(wm0 + m * 16 + lr) * 32 + sw8]);
#pragma unroll
        for (int n = 0; n < 2; ++n)
            bfv[n] = *reinterpret_cast<const bf16x8*>(&bs[(wn0 + n * 16 + lr) * 32 + sw8]);
#pragma unroll
        for (int m = 0; m < 4; ++m)
#pragma unroll
            for (int n = 0; n < 2; ++n)
                acc[m][n] = __builtin_amdgcn_mfma_f32_16x16x32_bf16(af[m], bfv[n], acc[m][n], 0, 0, 0);
    };

    for (int t = 0; t < NT; t += 2) { iter(t, a0); iter(t + 1, a1); }
    __syncthreads();

    const int cr = (lane >> 4) << 2;
    const int cc = lane & 15;
    float sacc[2] = {0.f, 0.f}, qacc[2] = {0.f, 0.f};
#pragma unroll
    for (int m = 0; m < 4; ++m) {
#pragma unroll
        for (int n = 0; n < 2; ++n) {
            int gcol = n0 + wn0 + n * 16 + cc;
            if (EPI == 0 || gcol < Nvalid) {
                float bv = bias[gcol];
                int grow = m0 + wm0 + m * 16 + cr;
#pragma unroll
                for (int j = 0; j < 4; ++j) {
                    float v = acc[m][n][j] + bv;
                    if (EPI == 1) {
                        float sg = 1.f / (1.f + __expf(-v));
                        v = 2.f * __expf(POWEXP * __logf(sg)) + 1e-7f;
                    } else {
                        sacc[n] += v;
                        qacc[n] += v * v;
                    }
                    C[(size_t)(grow + j) * ldc + gcol] = fbf16(v);
                }
            }
        }
    }
    if (EPI == 0) {
#pragma unroll
        for (int n = 0; n < 2; ++n) {
            float s = sacc[n], q = qacc[n];
            s += __shfl_xor(s, 16); q += __shfl_xor(q, 16);
            s += __shfl_xor(s, 32); q += __shfl_xor(q, 32);
            if (lane < 16) { sred[wid][n][lane] = s; qred[wid][n][lane] = q; }
        }
        __syncthreads();
        if (tid < 128) {
            int wn_ = tid >> 5, n_ = (tid >> 4) & 1, cc_ = tid & 15;
            float s = sred[wn_][n_][cc_] + sred[4 + wn_][n_][cc_];
            float q = qred[wn_][n_][cc_] + qred[4 + wn_][n_][cc_];
            int col = n0 + wn_ * 32 + n_ * 16 + cc_;
            psOut[(size_t)by * 512 + col] = s;
            pqOut[(size_t)by * 512 + col] = q;
        }
    }
}

// ---------------- batched input prep: 4 weight transposes + z cast --------
__global__ __launch_bounds__(256) void prep_inputs(
    const float* __restrict__ w0, const float* __restrict__ w1,
    const float* __restrict__ w2, const float* __restrict__ w3,
    const float* __restrict__ z,
    ushort* __restrict__ B0, ushort* __restrict__ B1,
    ushort* __restrict__ B2, ushort* __restrict__ B3,
    ushort* __restrict__ A)
{
    if (blockIdx.z == 4) {
        int bid = blockIdx.y * gridDim.x + blockIdx.x;
        if (bid >= 512) return;
        int idx = (bid * 256 + threadIdx.x) << 3;
        float4 a = *reinterpret_cast<const float4*>(&z[idx]);
        float4 b = *reinterpret_cast<const float4*>(&z[idx + 4]);
        float x[8] = {a.x, a.y, a.z, a.w, b.x, b.y, b.z, b.w};
        u16x8 o;
#pragma unroll
        for (int j = 0; j < 8; ++j) o[j] = fbf16(x[j]);
        *reinterpret_cast<u16x8*>(&A[idx]) = o;
        return;
    }
    const float* w; ushort* Bt; int K, N, GX, GY;
    switch (blockIdx.z) {
        case 0: w = w0; Bt = B0; K = 128; N = 512;  GX = 4;  GY = 16; break;
        case 1: w = w1; Bt = B1; K = 512; N = 512;  GX = 16; GY = 16; break;
        case 2: w = w2; Bt = B2; K = 512; N = 512;  GX = 16; GY = 16; break;
        default:w = w3; Bt = B3; K = 512; N = 1025; GX = 16; GY = 36; break;
    }
    if ((int)blockIdx.x >= GX || (int)blockIdx.y >= GY) return;
    __shared__ float tile[32][33];
    int k0 = blockIdx.x * 32, n0 = blockIdx.y * 32;
    int tx = threadIdx.x & 31, ty = threadIdx.x >> 5;
#pragma unroll
    for (int r = 0; r < 4; ++r) {
        int k = k0 + ty + r * 8;
        int n = n0 + tx;
        tile[ty + r * 8][tx] = (n < N) ? w[(size_t)k * N + n] : 0.f;
    }
    __syncthreads();
#pragma unroll
    for (int r = 0; r < 4; ++r) {
        int n = n0 + ty + r * 8;
        int k = k0 + tx;
        Bt[(size_t)n * K + k] = fbf16(tile[tx][ty + r * 8]);
    }
}

// ---------------- single-wave FFT filter: 1024 = 16x16x4 ------------------
// One wave64 per row; 16 points/lane; two in-register 16-pt DFTs + one LDS
// exchange + cross-lane radix-4 (DPP). Zero block barriers. H-multiply
// in-place (pairs (k,1024-k) are lane- and iteration-disjoint).
__global__ __launch_bounds__(64) void fft_filter_kernel(
    const float* __restrict__ noise, const ushort* __restrict__ fcsb,
    ushort* __restrict__ awb)
{
    __shared__ pf2 E[1056];
    __shared__ ushort F[1026];
    const int l = threadIdx.x;
    const int row = blockIdx.x;
    const int c = l & 3;
    const int k0 = l >> 2;                       // quad index (b-role in phase 1)
    const int rc = ((c & 1) << 1) | (c >> 1);    // cross-lane output digit

    // filter coeffs -> LDS
    const ushort* frow = fcsb + (size_t)row * 1040;
#pragma unroll
    for (int j = 0; j < 16; ++j) F[l + (j << 6)] = frow[l + (j << 6)];
    if (l == 0) F[1024] = frow[1024];

    pf2 v[16];
    // ---------------- forward FFT of packed noise ----------------
    {
        const pf2* nrow = reinterpret_cast<const pf2*>(noise + ((size_t)row << 11));
#pragma unroll
        for (int a = 0; a < 16; ++a) v[a] = nrow[(a << 6) + l];   // z[64a + l]
        dft16<false>(v);
        // T1 = W256^{b*k} (b = l>>2), recurrence
        {
            float rev = (float)(l >> 2) * (1.f / 256.f);
            float wc = vcos_rev(rev), ws = -vsin_rev(rev);
            float tc = wc, ts = ws;
            v[dsw(1)] = cmulp(v[dsw(1)], tc, ts);
#pragma unroll
            for (int k = 2; k < 16; ++k) {
                float ntc = tc * wc - ts * ws;
                ts = tc * ws + ts * wc; tc = ntc;
                v[dsw(k)] = cmulp(v[dsw(k)], tc, ts);
            }
        }
        // exchange: (b,c)-major -> (k0,c)-major
#pragma unroll
        for (int k = 0; k < 16; ++k) E[k * 66 + l] = v[dsw(k)];
        WAVE_FENCE();
#pragma unroll
        for (int b = 0; b < 16; ++b) v[b] = E[k0 * 66 + (b << 2) + c];
        dft16<false>(v);
        // T2 = W1024^{c*(k0 + 16*k1)}, recurrence
        {
            float rev0 = (float)(c * k0) * (1.f / 1024.f);
            float tc = vcos_rev(rev0), ts = -vsin_rev(rev0);
            float revs = (float)c * (1.f / 64.f);
            float wc = vcos_rev(revs), ws = -vsin_rev(revs);
            v[dsw(0)] = cmulp(v[dsw(0)], tc, ts);
#pragma unroll
            for (int k = 1; k < 16; ++k) {
                float ntc = tc * wc - ts * ws;
                ts = tc * ws + ts * wc; tc = ntc;
                v[dsw(k)] = cmulp(v[dsw(k)], tc, ts);
            }
        }
        WAVE_FENCE();
        // cross-lane radix-4 + spectrum store (natural order, S5 layout)
#pragma unroll
        for (int k1 = 0; k1 < 16; ++k1) {
            pf2 res = xl_radix4<false>(v[dsw(k1)], c);
            E[S5(k0 + (k1 << 4) + (rc << 8))] = res;
        }
    }
    WAVE_FENCE();
    // ---------------- H multiply, in-place pairwise ----------------
    {
        const float INV1024 = 1.0f / 1024.0f;
        auto procfn = [&](int k, float pc, float ps) {
            int k2 = (1024 - k) & 1023;
            pf2 za = E[S5(k)], zb = E[S5(k2)];
            float Fer = 0.5f * (za.x + zb.x), Fei = 0.5f * (za.y - zb.y);
            float For = 0.5f * (za.y + zb.y), Foi = 0.5f * (zb.x - za.x);
            float wFr = pc * For - ps * Foi;
            float wFi = pc * Foi + ps * For;
            float Xkr = Fer + wFr, Xki = Fei + wFi;
            float Xbr = Fer - wFr, Xbi = wFi - Fei;
            float Hk, Hb;
            {
                float cl = (k == 0) ? bf16f(F[1]) : bf16f(F[k - 1]);
                float crr = bf16f(F[k + 1]);
                float h = 0.5f * bf16f(F[k]) + 0.25f * (cl + crr);
                Hk = ((k & 1) ? -h : h) * INV1024;
            }
            {
                int kb = 1024 - k;
                float cl = bf16f(F[kb - 1]);
                float crr = (kb == 1024) ? bf16f(F[1023]) : bf16f(F[kb + 1]);
                float h = 0.5f * bf16f(F[kb]) + 0.25f * (cl + crr);
                Hb = ((kb & 1) ? -h : h) * INV1024;
            }
            float Ykr = Hk * Xkr, Yki = Hk * Xki;
            float Ybr = Hb * Xbr, Ybi = Hb * Xbi;
            if (k == 0) {
                E[S5(0)] = (pf2){0.5f * (Ykr + Ybr), 0.5f * (Ykr - Ybr)};
            } else {
                float Ger = 0.5f * (Ykr + Ybr), Gei = 0.5f * (Yki - Ybi);
                float Sgr = 0.5f * (Ykr - Ybr), Sgi = 0.5f * (Yki + Ybi);
                float wpr = pc, wpi = -ps;
                float Gor = wpr * Sgr - wpi * Sgi;
                float Goi = wpr * Sgi + wpi * Sgr;
                E[S5(k)]  = (pf2){Ger - Goi, Gei + Gor};
                E[S5(k2)] = (pf2){Ger + Goi, Gor - Gei};
            }
        };
#pragma unroll
        for (int j = 0; j < 8; ++j) {
            int k = l + (j << 6);
            float rev = (float)k * (1.f / 2048.f);
            procfn(k, vcos_rev(rev), -vsin_rev(rev));
        }
        if (l == 0) procfn(512, 0.f, -1.f);
    }
    WAVE_FENCE();
    // ---------------- inverse FFT + OLA window + bf16 store ----------------
    {
#pragma unroll
        for (int a = 0; a < 16; ++a) v[a] = E[S5((a << 6) + l)];
        dft16<true>(v);
        // T1 conj
        {
            float rev = (float)(l >> 2) * (1.f / 256.f);
            float wc = vcos_rev(rev), ws = vsin_rev(rev);
            float tc = wc, ts = ws;
            v[dsw(1)] = cmulp(v[dsw(1)], tc, ts);
#pragma unroll
            for (int k = 2; k < 16; ++k) {
                float ntc = tc * wc - ts * ws;
                ts = tc * ws + ts * wc; tc = ntc;
                v[dsw(k)] = cmulp(v[dsw(k)], tc, ts);
            }
        }
        WAVE_FENCE();
#pragma unroll
        for (int k = 0; k < 16; ++k) E[k * 66 + l] = v[dsw(k)];
        WAVE_FENCE();
#pragma unroll
        for (int b = 0; b < 16; ++b) v[b] = E[k0 * 66 + (b << 2) + c];
        dft16<true>(v);
        // T2 conj
        {
            float rev0 = (float)(c * k0) * (1.f / 1024.f);
            float tc = vcos_rev(rev0), ts = vsin_rev(rev0);
            float revs = (float)c * (1.f / 64.f);
            float wc = vcos_rev(revs), ws = vsin_rev(revs);
            v[dsw(0)] = cmulp(v[dsw(0)], tc, ts);
#pragma unroll
            for (int k = 1; k < 16; ++k) {
                float ntc = tc * wc - ts * ws;
                ts = tc * ws + ts * wc; tc = ntc;
                v[dsw(k)] = cmulp(v[dsw(k)], tc, ts);
            }
        }
        const int g = row & 511;
        ushort2* awrow = reinterpret_cast<ushort2*>(awb + ((size_t)row << 11));
        const float COSD = 0.99999529380958f;   // cos(pi/1024)
        const float SIND = 0.00306795676296f;   // sin(pi/1024)
#pragma unroll
        for (int k1 = 0; k1 < 16; ++k1) {
            pf2 res = xl_radix4<true>(v[dsw(k1)], c);
            int i = k0 + (k1 << 4) + (rc << 8);   // complex time index
            float w0, w1;
            bool edge = (g == 0 && i < 512) || (g == 511 && i >= 512);
            if (edge) { w0 = 1.f; w1 = 1.f; }
            else {
                float rev = (float)i * (1.f / 1024.f);
                float ci = vcos_rev(rev), si = vsin_rev(rev);
                w0 = 0.5f - 0.5f * ci;
                w1 = 0.5f - 0.5f * (ci * COSD - si * SIND);
            }
            ushort2 ov; ov.x = fbf16(res.x * w0); ov.y = fbf16(res.y * w1);
            awrow[i] = ov;
        }
    }
}

// ---------------- fused OLA gather + 65-tap conv + softsign ---------------
__global__ __launch_bounds__(256) void ola_ppconv_kernel(
    const ushort* __restrict__ awb, const float* __restrict__ ppw,
    const float* __restrict__ ppb, float* __restrict__ out)
{
    __shared__ float tile[320];
    __shared__ float Ksh[65];
    int t0 = blockIdx.x * 256;
    int b = blockIdx.y;
    const ushort* awbase = awb + ((size_t)(b * 512) << 11);
    for (int i = threadIdx.x; i < 320; i += 256) {
        int tt = t0 - 32 + i;
        float v = 0.f;
        if (tt >= 1536 && tt < 262144) {
            int glo = (tt - 1536) >> 9;
            const ushort* p = awbase + ((size_t)glo << 11) + (tt - (glo << 9));
            float s = bf16f(p[0]) + bf16f(p[1536]) + bf16f(p[3072]) + bf16f(p[4608]);
            v = s * 0.25f;
        } else if (tt >= 0 && tt < TARLEN) {
            int ghi = min(511, tt >> 9);
            int glo = max(0, (tt - 1536) >> 9);
            float s = 0.f;
            for (int g = glo; g <= ghi; ++g) {
                int n = tt - (g << 9);
                s += bf16f(awbase[((size_t)g << 11) + n]);
            }
            v = s / (float)(ghi - glo + 1);
        }
        tile[i] = v;
    }
    if (threadIdx.x < 65) {
        float k = 0.f;
#pragma unroll
        for (int c = 0; c < 5; ++c) k += ppw[c * 65 + threadIdx.x];
        Ksh[threadIdx.x] = k;
    }
    __syncthreads();
    float y = ppb[0];
#pragma unroll
    for (int j = 0; j < 65; ++j) y = fmaf(Ksh[j], tile[threadIdx.x + j], y);
    int t = t0 + threadIdx.x;
    out[(size_t)b * TARLEN + t] = y / (1.f + fabsf(y));
}

// ---------------- launch --------------------------------------------------
extern "C" void kernel_launch(void* const* d_in, const int* in_sizes, int n_in,
                              void* d_out, int out_size, void* d_ws, size_t ws_size,
                              hipStream_t stream) {
    const float* z    = (const float*)d_in[0];
    const float* w0   = (const float*)d_in[1];
    const float* b0   = (const float*)d_in[2];
    const float* g0   = (const float*)d_in[3];
    const float* be0  = (const float*)d_in[4];
    const float* w1   = (const float*)d_in[5];
    const float* b1   = (const float*)d_in[6];
    const float* g1   = (const float*)d_in[7];
    const float* be1  = (const float*)d_in[8];
    const float* w2   = (const float*)d_in[9];
    const float* b2   = (const float*)d_in[10];
    const float* g2   = (const float*)d_in[11];
    const float* be2  = (const float*)d_in[12];
    const float* w3   = (const float*)d_in[13];
    const float* b3   = (const float*)d_in[14];
    const float* ppw  = (const float*)d_in[15];
    const float* ppb  = (const float*)d_in[16];
    const float* noise= (const float*)d_in[17];
    float* out = (float*)d_out;
    float* ws = (float*)d_ws;

    // workspace (float offsets)
    ushort* h0b = (ushort*)ws;                    // 8192*512 bf16
    ushort* h1b = (ushort*)(ws + 2097152);        // 8192*512 bf16
    float* ps0  = ws + 4194304;                   // 64*512
    float* pq0  = ps0 + 32768;
    float* ps1  = pq0 + 32768;
    float* pq1  = ps1 + 32768;
    float* base = pq1 + 32768;
    ushort* Bt0 = (ushort*)base;                  // 512*128 bf16
    ushort* Bt1 = (ushort*)(base + 32768);        // 512*512 bf16
    ushort* Bt2 = (ushort*)(base + 163840);       // 512*512 bf16
    ushort* Bt3 = (ushort*)(base + 294912);       // 1152*512 bf16
    ushort* fcsb= (ushort*)(base + 589824);       // 8192*1040 bf16
    ushort* awb = (ushort*)(base + 4849664);      // 8192*2048 bf16
    ushort* A   = (ushort*)(base + 13238272);     // 8192*128 bf16 (z cast)
    ushort* h2b = h0b;  // h0 dead after gemm1 consumed it

    dim3 blk(256);
    dim3 gblk(512);
    // input prep (4 weight transposes + z cast) in one launch
    prep_inputs<<<dim3(16, 36, 5), blk, 0, stream>>>(
        w0, w1, w2, w3, z, Bt0, Bt1, Bt2, Bt3, A);
    // layer 0: h0 = z @ w0 + b0 (+ stats -> S0); K=128
    gemm8<<<dim3(4, 64), gblk, 0, stream>>>(A, Bt0, b0, h0b, 128, ps0, pq0);
    // layer 1: fused BN(S0)+lrelu on A, gemm, stats -> S1
    gemm8n<0><<<dim3(4, 64), gblk, 0, stream>>>(
        h0b, Bt1, b1, ps0, pq0, g0, be0, h1b, 512, 512, 512, ps1, pq1);
    // layer 2: fused BN(S1), stats -> S0
    gemm8n<0><<<dim3(4, 64), gblk, 0, stream>>>(
        h1b, Bt2, b2, ps1, pq1, g1, be1, h2b, 512, 512, 512, ps0, pq0);
    // layer 3: fused BN(S0), mod_sigmoid -> fcsb [8192][1040], 1025 valid
    gemm8n<1><<<dim3(9, 64), gblk, 0, stream>>>(
        h2b, Bt3, b3, ps0, pq0, g2, be2, fcsb, 512, 1025, 1040, nullptr, nullptr);
    // spectral filtering + window: one wave per row
    fft_filter_kernel<<<dim3(8192), dim3(64), 0, stream>>>(noise, fcsb, awb);
    // fused OLA + post conv + softsign
    ola_ppconv_kernel<<<dim3(1030, 16), blk, 0, stream>>>(awb, ppw, ppb, out);
    (void)in_sizes; (void)n_in; (void)out_size; (void)ws_size;
}

// Round 16
// 159.212 us; speedup vs baseline: 1.0479x; 1.0479x over previous
//
#include <hip/hip_runtime.h>
#include <hip/hip_bf16.h>
#include <math.h>

#define TARLEN 263680
#define POWEXP 2.302585092994046f  // ln(10)
#define PC(i) ((i) + ((i) >> 3))   // complex-unit LDS padding (1 per 8)

typedef __attribute__((ext_vector_type(8))) short bf16x8;
typedef __attribute__((ext_vector_type(8))) ushort u16x8;
typedef __attribute__((ext_vector_type(4))) float f32x4;

__device__ __forceinline__ void gload16(const void* g, void* l) {
    __builtin_amdgcn_global_load_lds((const __attribute__((address_space(1))) void*)g,
                                     (__attribute__((address_space(3))) void*)l, 16, 0, 0);
}

__device__ __forceinline__ float bf16f(ushort u) {
    union { uint u; float f; } v; v.u = (uint)u << 16; return v.f;
}
__device__ __forceinline__ ushort fbf16(float x) {
    __hip_bfloat16 h = __float2bfloat16(x);
    return *reinterpret_cast<ushort*>(&h);
}

// sin/cos with input in REVOLUTIONS (v_sin_f32 native domain); args are exact
// binary fractions -> no rounding, no range reduction.
__device__ __forceinline__ float vsin_rev(float rev) {
    float r; asm("v_sin_f32 %0, %1" : "=v"(r) : "v"(rev)); return r;
}
__device__ __forceinline__ float vcos_rev(float rev) {
    float r; asm("v_cos_f32 %0, %1" : "=v"(r) : "v"(rev)); return r;
}

// ============ GEMM layer 0 (no norm): 128x128 tile, 512 thr =================
__global__ __launch_bounds__(512) void gemm8(
    const ushort* __restrict__ A, const ushort* __restrict__ Bt,
    const float* __restrict__ bias, ushort* __restrict__ C,
    int K, float* __restrict__ ps, float* __restrict__ pq)
{
    __shared__ ushort As[3][4096];
    __shared__ ushort Bs[3][4096];
    __shared__ float sred[8][2][16];
    __shared__ float qred[8][2][16];
    const int tid = threadIdx.x;
    const int lane = tid & 63;
    const int wid = tid >> 6;
    const int nwg = gridDim.x * gridDim.y;
    const int bid = blockIdx.y * gridDim.x + blockIdx.x;
    const int q8 = nwg >> 3;
    const int swzb = (bid & 7) * q8 + (bid >> 3);
    const int bx = swzb % gridDim.x;
    const int by = swzb / gridDim.x;
    const int m0 = by * 128;
    const int n0 = bx * 128;
    const int NT = K >> 5;

    f32x4 acc[4][2];
#pragma unroll
    for (int m = 0; m < 4; ++m)
#pragma unroll
        for (int n = 0; n < 2; ++n)
            acc[m][n] = (f32x4){0.f, 0.f, 0.f, 0.f};

    const int srow = tid >> 2;
    const int scol = (((tid & 3) ^ ((tid >> 3) & 3)) << 3);

    auto stage = [&](int t, int buf) {
        const int k0 = t << 5;
        gload16(A + (size_t)(m0 + srow) * K + k0 + scol, &As[buf][tid * 8]);
        gload16(Bt + (size_t)(n0 + srow) * K + k0 + scol, &Bs[buf][tid * 8]);
    };

    const int lr = lane & 15;
    const int sw8 = (((lane >> 4) ^ ((lane >> 1) & 3)) << 3);
    const int wm0 = (wid >> 2) * 64;
    const int wn0 = (wid & 3) * 32;

    stage(0, 0);
    stage(1, 1);
    for (int t = 0; t < NT; ++t) {
        const int cur = t % 3;
        if (t + 2 < NT) {
            asm volatile("s_waitcnt vmcnt(2)" ::: "memory");
            __builtin_amdgcn_s_barrier();
            stage(t + 2, (t + 2) % 3);
        } else {
            asm volatile("s_waitcnt vmcnt(0)" ::: "memory");
            __builtin_amdgcn_s_barrier();
        }
        const ushort* as = As[cur];
        const ushort* bs = Bs[cur];
        bf16x8 af[4], bfv[2];
#pragma unroll
        for (int m = 0; m < 4; ++m)
            af[m] = *reinterpret_cast<const bf16x8*>(&as[(wm0 + m * 16 + lr) * 32 + sw8]);
#pragma unroll
        for (int n = 0; n < 2; ++n)
            bfv[n] = *reinterpret_cast<const bf16x8*>(&bs[(wn0 + n * 16 + lr) * 32 + sw8]);
#pragma unroll
        for (int m = 0; m < 4; ++m)
#pragma unroll
            for (int n = 0; n < 2; ++n)
                acc[m][n] = __builtin_amdgcn_mfma_f32_16x16x32_bf16(af[m], bfv[n], acc[m][n], 0, 0, 0);
    }
    __syncthreads();

    const int cr = (lane >> 4) << 2;
    const int cc = lane & 15;
    float sacc[2] = {0.f, 0.f}, qacc[2] = {0.f, 0.f};
#pragma unroll
    for (int m = 0; m < 4; ++m) {
#pragma unroll
        for (int n = 0; n < 2; ++n) {
            int gcol = n0 + wn0 + n * 16 + cc;
            float bv = bias[gcol];
            int grow = m0 + wm0 + m * 16 + cr;
#pragma unroll
            for (int j = 0; j < 4; ++j) {
                float v = acc[m][n][j] + bv;
                sacc[n] += v;
                qacc[n] += v * v;
                C[(size_t)(grow + j) * 512 + gcol] = fbf16(v);
            }
        }
    }
#pragma unroll
    for (int n = 0; n < 2; ++n) {
        float s = sacc[n], q = qacc[n];
        s += __shfl_xor(s, 16); q += __shfl_xor(q, 16);
        s += __shfl_xor(s, 32); q += __shfl_xor(q, 32);
        if (lane < 16) { sred[wid][n][lane] = s; qred[wid][n][lane] = q; }
    }
    __syncthreads();
    if (tid < 128) {
        int wn_ = tid >> 5, n_ = (tid >> 4) & 1, cc_ = tid & 15;
        float s = sred[wn_][n_][cc_] + sred[4 + wn_][n_][cc_];
        float q = qred[wn_][n_][cc_] + qred[4 + wn_][n_][cc_];
        int col = n0 + wn_ * 32 + n_ * 16 + cc_;
        ps[(size_t)by * 512 + col] = s;
        pq[(size_t)by * 512 + col] = q;
    }
}

// ============ GEMM with fused BN (stats reduce + affine + lrelu on A) =======
template<int EPI>
__global__ __launch_bounds__(512) void gemm8n(
    const ushort* __restrict__ H, const ushort* __restrict__ Bt,
    const float* __restrict__ bias,
    const float* __restrict__ psIn, const float* __restrict__ pqIn,
    const float* __restrict__ gamma, const float* __restrict__ beta,
    ushort* __restrict__ C, int K, int Nvalid, int ldc,
    float* __restrict__ psOut, float* __restrict__ pqOut)
{
    __shared__ ushort As[3][4096];
    __shared__ ushort Bs[3][4096];
    __shared__ uint sab[512];
    __shared__ float sred[8][2][16];
    __shared__ float qred[8][2][16];
    const int tid = threadIdx.x;
    const int lane = tid & 63;
    const int wid = tid >> 6;
    const int nwg = gridDim.x * gridDim.y;
    const int bid = blockIdx.y * gridDim.x + blockIdx.x;
    const int q8 = nwg >> 3;
    const int swzb = (bid & 7) * q8 + (bid >> 3);
    const int bx = swzb % gridDim.x;
    const int by = swzb / gridDim.x;
    const int m0 = by * 128;
    const int n0 = bx * 128;
    const int NT = K >> 5;  // even (K=512)

    {
        int c = tid;
        float s = 0.f, q = 0.f;
#pragma unroll 8
        for (int rg = 0; rg < 64; ++rg) { s += psIn[rg * 512 + c]; q += pqIn[rg * 512 + c]; }
        float m = s * (1.f / 8192.f);
        float v = q * (1.f / 8192.f) - m * m;
        float a = rsqrtf(v + 1e-5f) * gamma[c];
        float b = beta[c] - m * a;
        sab[c] = (uint)fbf16(a) | ((uint)fbf16(b) << 16);
    }

    f32x4 acc[4][2];
#pragma unroll
    for (int m = 0; m < 4; ++m)
#pragma unroll
        for (int n = 0; n < 2; ++n)
            acc[m][n] = (f32x4){0.f, 0.f, 0.f, 0.f};

    const int srow = tid >> 2;
    const int scol = (((tid & 3) ^ ((tid >> 3) & 3)) << 3);
    const int lr = lane & 15;
    const int sw8 = (((lane >> 4) ^ ((lane >> 1) & 3)) << 3);
    const int wm0 = (wid >> 2) * 64;
    const int wn0 = (wid & 3) * 32;

    const size_t arow = (size_t)(m0 + srow) * K + scol;
    const size_t brow = (size_t)(n0 + srow) * K + scol;

    auto stageB = [&](int t, int buf) {
        gload16(Bt + brow + (t << 5), &Bs[buf][tid * 8]);
    };
    auto loadA = [&](int t, u16x8& dst) {
        dst = *reinterpret_cast<const u16x8*>(H + arow + (t << 5));
    };

    __syncthreads();  // sab ready

    u16x8 a0, a1;
    stageB(0, 0); loadA(0, a0);
    stageB(1, 1); loadA(1, a1);

    auto iter = [&](int t, u16x8& ar) {
        const int cur = t % 3;
        if (t + 2 < NT) asm volatile("s_waitcnt vmcnt(2)" ::: "memory");
        else            asm volatile("s_waitcnt vmcnt(0)" ::: "memory");
        {
            const uint* pk = &sab[(t << 5) + scol];
            u16x8 o;
#pragma unroll
            for (int j = 0; j < 8; ++j) {
                uint w = pk[j];
                float a = bf16f((ushort)(w & 0xffffu));
                float b = bf16f((ushort)(w >> 16));
                float y = fmaf(bf16f(ar[j]), a, b);
                o[j] = fbf16(y >= 0.f ? y : 0.2f * y);
            }
            *reinterpret_cast<u16x8*>(&As[cur][tid * 8]) = o;
        }
        asm volatile("s_waitcnt lgkmcnt(0)" ::: "memory");
        __builtin_amdgcn_s_barrier();
        if (t + 2 < NT) { stageB(t + 2, (t + 2) % 3); loadA(t + 2, ar); }
        const ushort* as = As[cur];
        const ushort* bs = Bs[cur];
        bf16x8 af[4], bfv[2];
#pragma unroll
        for (int m = 0; m < 4; ++m)
            af[m] = *reinterpret_cast<const bf16x8*>(&as[(wm0 + m * 16 + lr) * 32 + sw8]);
#pragma unroll
        for (int n = 0; n < 2; ++n)
            bfv[n] = *reinterpret_cast<const bf16x8*>(&bs[(wn0 + n * 16 + lr) * 32 + sw8]);
#pragma unroll
        for (int m = 0; m < 4; ++m)
#pragma unroll
            for (int n = 0; n < 2; ++n)
                acc[m][n] = __builtin_amdgcn_mfma_f32_16x16x32_bf16(af[m], bfv[n], acc[m][n], 0, 0, 0);
    };

    for (int t = 0; t < NT; t += 2) { iter(t, a0); iter(t + 1, a1); }
    __syncthreads();

    const int cr = (lane >> 4) << 2;
    const int cc = lane & 15;
    float sacc[2] = {0.f, 0.f}, qacc[2] = {0.f, 0.f};
#pragma unroll
    for (int m = 0; m < 4; ++m) {
#pragma unroll
        for (int n = 0; n < 2; ++n) {
            int gcol = n0 + wn0 + n * 16 + cc;
            if (EPI == 0 || gcol < Nvalid) {
                float bv = bias[gcol];
                int grow = m0 + wm0 + m * 16 + cr;
#pragma unroll
                for (int j = 0; j < 4; ++j) {
                    float v = acc[m][n][j] + bv;
                    if (EPI == 1) {
                        float sg = 1.f / (1.f + __expf(-v));
                        v = 2.f * __expf(POWEXP * __logf(sg)) + 1e-7f;
                    } else {
                        sacc[n] += v;
                        qacc[n] += v * v;
                    }
                    C[(size_t)(grow + j) * ldc + gcol] = fbf16(v);
                }
            }
        }
    }
    if (EPI == 0) {
#pragma unroll
        for (int n = 0; n < 2; ++n) {
            float s = sacc[n], q = qacc[n];
            s += __shfl_xor(s, 16); q += __shfl_xor(q, 16);
            s += __shfl_xor(s, 32); q += __shfl_xor(q, 32);
            if (lane < 16) { sred[wid][n][lane] = s; qred[wid][n][lane] = q; }
        }
        __syncthreads();
        if (tid < 128) {
            int wn_ = tid >> 5, n_ = (tid >> 4) & 1, cc_ = tid & 15;
            float s = sred[wn_][n_][cc_] + sred[4 + wn_][n_][cc_];
            float q = qred[wn_][n_][cc_] + qred[4 + wn_][n_][cc_];
            int col = n0 + wn_ * 32 + n_ * 16 + cc_;
            psOut[(size_t)by * 512 + col] = s;
            pqOut[(size_t)by * 512 + col] = q;
        }
    }
}

// ---------------- batched input prep: 4 weight transposes + z cast --------
__global__ __launch_bounds__(256) void prep_inputs(
    const float* __restrict__ w0, const float* __restrict__ w1,
    const float* __restrict__ w2, const float* __restrict__ w3,
    const float* __restrict__ z,
    ushort* __restrict__ B0, ushort* __restrict__ B1,
    ushort* __restrict__ B2, ushort* __restrict__ B3,
    ushort* __restrict__ A)
{
    if (blockIdx.z == 4) {
        int bid = blockIdx.y * gridDim.x + blockIdx.x;
        if (bid >= 512) return;
        int idx = (bid * 256 + threadIdx.x) << 3;
        float4 a = *reinterpret_cast<const float4*>(&z[idx]);
        float4 b = *reinterpret_cast<const float4*>(&z[idx + 4]);
        float x[8] = {a.x, a.y, a.z, a.w, b.x, b.y, b.z, b.w};
        u16x8 o;
#pragma unroll
        for (int j = 0; j < 8; ++j) o[j] = fbf16(x[j]);
        *reinterpret_cast<u16x8*>(&A[idx]) = o;
        return;
    }
    const float* w; ushort* Bt; int K, N, GX, GY;
    switch (blockIdx.z) {
        case 0: w = w0; Bt = B0; K = 128; N = 512;  GX = 4;  GY = 16; break;
        case 1: w = w1; Bt = B1; K = 512; N = 512;  GX = 16; GY = 16; break;
        case 2: w = w2; Bt = B2; K = 512; N = 512;  GX = 16; GY = 16; break;
        default:w = w3; Bt = B3; K = 512; N = 1025; GX = 16; GY = 36; break;
    }
    if ((int)blockIdx.x >= GX || (int)blockIdx.y >= GY) return;
    __shared__ float tile[32][33];
    int k0 = blockIdx.x * 32, n0 = blockIdx.y * 32;
    int tx = threadIdx.x & 31, ty = threadIdx.x >> 5;
#pragma unroll
    for (int r = 0; r < 4; ++r) {
        int k = k0 + ty + r * 8;
        int n = n0 + tx;
        tile[ty + r * 8][tx] = (n < N) ? w[(size_t)k * N + n] : 0.f;
    }
    __syncthreads();
#pragma unroll
    for (int r = 0; r < 4; ++r) {
        int n = n0 + ty + r * 8;
        int k = k0 + tx;
        Bt[(size_t)n * K + k] = fbf16(tile[tx][ty + r * 8]);
    }
}

// ---------------- Stockham radix-4 FFT, float2 LDS, 256 threads (r11) -----
__device__ __forceinline__ float2 cmul(float2 a, float c, float s) {
    return make_float2(a.x * c - a.y * s, a.x * s + a.y * c);
}

template<bool INV, int L>
__device__ __forceinline__ void stk_stage(
    const float2* __restrict__ s, float2* __restrict__ d, int t)
{
    int k = t & (L - 1);
    float2 x0 = s[PC(t)];
    float2 x1 = s[PC(t + 256)];
    float2 x2 = s[PC(t + 512)];
    float2 x3 = s[PC(t + 768)];
    if (L > 1) {
        float rev = (float)k * (1.0f / (float)(4 * L));
        float s1 = vsin_rev(rev), c1 = vcos_rev(rev);
        if (!INV) s1 = -s1;
        float c2 = c1 * c1 - s1 * s1, s2 = 2.f * c1 * s1;
        float c3 = c2 * c1 - s2 * s1, s3 = s2 * c1 + c2 * s1;
        x1 = cmul(x1, c1, s1);
        x2 = cmul(x2, c2, s2);
        x3 = cmul(x3, c3, s3);
    }
    float2 a = make_float2(x0.x + x2.x, x0.y + x2.y);
    float2 b = make_float2(x0.x - x2.x, x0.y - x2.y);
    float2 c = make_float2(x1.x + x3.x, x1.y + x3.y);
    float2 e = make_float2(x1.x - x3.x, x1.y - x3.y);
    int db = ((t - k) << 2) + k;
    d[PC(db)]         = make_float2(a.x + c.x, a.y + c.y);
    d[PC(db + 2 * L)] = make_float2(a.x - c.x, a.y - c.y);
    if (!INV) {
        d[PC(db + L)]     = make_float2(b.x + e.y, b.y - e.x);
        d[PC(db + 3 * L)] = make_float2(b.x - e.y, b.y + e.x);
    } else {
        d[PC(db + L)]     = make_float2(b.x - e.y, b.y + e.x);
        d[PC(db + 3 * L)] = make_float2(b.x + e.y, b.y - e.x);
    }
}

// audio = irfft( rfft(noise_row) * H ), H[k] = (-1)^k*(0.5 fc[k]+0.25 fc[k-1]+0.25 fc[k+1])
// (analytic collapse of rfft(fftshift(irfft(fc)*FW))). 1/1024 folded into H.
// fcs read as bf16; aw written as bf16. OLA window from final-stage twiddle.
__global__ __launch_bounds__(256) void fft_filter_kernel(
    const float* __restrict__ noise, const ushort* __restrict__ fcsb,
    ushort* __restrict__ awb)
{
    __shared__ float2 X[1152], Y[1152];
    __shared__ float F[1025];
    const int tid = threadIdx.x;
    const int r = blockIdx.x;

    const float2* nrow = reinterpret_cast<const float2*>(noise + ((size_t)r << 11));
    for (int i = tid; i < 1025; i += 256) F[i] = bf16f(fcsb[(size_t)r * 1040 + i]);
    {
        // forward stage L=1 fused with global load (pack z[n]=x[2n]+i x[2n+1])
        float2 x0 = nrow[tid], x1 = nrow[tid + 256], x2 = nrow[tid + 512], x3 = nrow[tid + 768];
        float2 a = make_float2(x0.x + x2.x, x0.y + x2.y);
        float2 b = make_float2(x0.x - x2.x, x0.y - x2.y);
        float2 c = make_float2(x1.x + x3.x, x1.y + x3.y);
        float2 e = make_float2(x1.x - x3.x, x1.y - x3.y);
        int db = tid << 2;
        Y[PC(db)]     = make_float2(a.x + c.x, a.y + c.y);
        Y[PC(db + 1)] = make_float2(b.x + e.y, b.y - e.x);
        Y[PC(db + 2)] = make_float2(a.x - c.x, a.y - c.y);
        Y[PC(db + 3)] = make_float2(b.x - e.y, b.y + e.x);
    }
    __syncthreads();
    stk_stage<false, 4>(Y, X, tid);   __syncthreads();
    stk_stage<false, 16>(X, Y, tid);  __syncthreads();
    stk_stage<false, 64>(Y, X, tid);  __syncthreads();
    stk_stage<false, 256>(X, Y, tid); __syncthreads();
    // forward result in Y (natural order)

    const float INV1024 = 1.0f / 1024.0f;
    auto proc = [&](int k, float c, float s) {
        int k2 = (1024 - k) & 1023;
        float2 za = Y[PC(k)], zb = Y[PC(k2)];
        float Fer = 0.5f * (za.x + zb.x), Fei = 0.5f * (za.y - zb.y);
        float For = 0.5f * (za.y + zb.y), Foi = 0.5f * (zb.x - za.x);
        float wFr = c * For - s * Foi;
        float wFi = c * Foi + s * For;
        float Xkr = Fer + wFr, Xki = Fei + wFi;
        float Xbr = Fer - wFr, Xbi = wFi - Fei;
        float Hk, Hb;
        {
            float cl = (k == 0) ? F[1] : F[k - 1];
            float crr = (k == 1024) ? F[1023] : F[k + 1];
            float h = 0.5f * F[k] + 0.25f * (cl + crr);
            Hk = ((k & 1) ? -h : h) * INV1024;
        }
        {
            int kb = 1024 - k;
            float cl = (kb == 0) ? F[1] : F[kb - 1];
            float crr = (kb == 1024) ? F[1023] : F[kb + 1];
            float h = 0.5f * F[kb] + 0.25f * (cl + crr);
            Hb = ((kb & 1) ? -h : h) * INV1024;
        }
        float Ykr = Hk * Xkr, Yki = Hk * Xki;
        float Ybr = Hb * Xbr, Ybi = Hb * Xbi;
        if (k == 0) {
            X[PC(0)] = make_float2(0.5f * (Ykr + Ybr), 0.5f * (Ykr - Ybr));
        } else {
            float Ger = 0.5f * (Ykr + Ybr), Gei = 0.5f * (Yki - Ybi);
            float Sgr = 0.5f * (Ykr - Ybr), Sgi = 0.5f * (Yki + Ybi);
            float wpr = c, wpi = -s;
            float Gor = wpr * Sgr - wpi * Sgi;
            float Goi = wpr * Sgi + wpi * Sgr;
            X[PC(k)]  = make_float2(Ger - Goi, Gei + Gor);
            X[PC(k2)] = make_float2(Ger + Goi, Gor - Gei);
        }
    };
    {
        // w = e^{-i pi k/1024}: rev = k/2048 (exact), sin negated
        float rev0 = (float)tid * (1.0f / 2048.0f);
        float c0 = vcos_rev(rev0), s0 = -vsin_rev(rev0);
        proc(tid, c0, s0);
        float rev1 = (float)(tid + 256) * (1.0f / 2048.0f);
        float c1 = vcos_rev(rev1), s1 = -vsin_rev(rev1);
        proc(tid + 256, c1, s1);
        if (tid == 0) proc(512, 0.f, -1.f);
    }
    __syncthreads();

    stk_stage<true, 1>(X, Y, tid);  __syncthreads();
    stk_stage<true, 4>(Y, X, tid);  __syncthreads();
    stk_stage<true, 16>(X, Y, tid); __syncthreads();
    stk_stage<true, 64>(Y, X, tid); __syncthreads();

    // inverse final stage (L=256) fused with OLA window + bf16 store
    {
        const int g = r & 511;
        ushort2* awrow = reinterpret_cast<ushort2*>(awb + ((size_t)r << 11));
        int t = tid;
        float2 x0 = X[PC(t)], x1 = X[PC(t + 256)], x2 = X[PC(t + 512)], x3 = X[PC(t + 768)];
        float rev = (float)t * (1.0f / 1024.0f);
        float s1 = vsin_rev(rev), c1 = vcos_rev(rev);
        float c2 = c1 * c1 - s1 * s1, s2 = 2.f * c1 * s1;
        float c3 = c2 * c1 - s2 * s1, s3 = s2 * c1 + c2 * s1;
        x1 = cmul(x1, c1, s1);
        x2 = cmul(x2, c2, s2);
        x3 = cmul(x3, c3, s3);
        float2 a = make_float2(x0.x + x2.x, x0.y + x2.y);
        float2 b = make_float2(x0.x - x2.x, x0.y - x2.y);
        float2 c = make_float2(x1.x + x3.x, x1.y + x3.y);
        float2 e = make_float2(x1.x - x3.x, x1.y - x3.y);
        float2 o[4];
        o[0] = make_float2(a.x + c.x, a.y + c.y);
        o[1] = make_float2(b.x - e.y, b.y + e.x);
        o[2] = make_float2(a.x - c.x, a.y - c.y);
        o[3] = make_float2(b.x + e.y, b.y - e.x);
        float cq[4] = {c1, -s1, -c1, s1};
        float sq[4] = {s1, c1, -s1, -c1};
        const float COSD = 0.99999529380958f;   // cos(pi/1024)
        const float SIND = 0.00306795676296f;   // sin(pi/1024)
#pragma unroll
        for (int q = 0; q < 4; ++q) {
            int n = t + 256 * q;
            float w0, w1;
            bool edge = (g == 0 && q < 2) || (g == 511 && q >= 2);
            if (edge) { w0 = 1.f; w1 = 1.f; }
            else {
                w0 = 0.5f - 0.5f * cq[q];
                w1 = 0.5f - 0.5f * (cq[q] * COSD - sq[q] * SIND);
            }
            ushort2 ov; ov.x = fbf16(o[q].x * w0); ov.y = fbf16(o[q].y * w1);
            awrow[n] = ov;
        }
    }
}

// ---------------- fused OLA gather + 65-tap conv + softsign ---------------
__global__ __launch_bounds__(256) void ola_ppconv_kernel(
    const ushort* __restrict__ awb, const float* __restrict__ ppw,
    const float* __restrict__ ppb, float* __restrict__ out)
{
    __shared__ float tile[320];
    __shared__ float Ksh[65];
    int t0 = blockIdx.x * 256;
    int b = blockIdx.y;
    const ushort* awbase = awb + ((size_t)(b * 512) << 11);
    for (int i = threadIdx.x; i < 320; i += 256) {
        int tt = t0 - 32 + i;
        float v = 0.f;
        if (tt >= 1536 && tt < 262144) {
            int glo = (tt - 1536) >> 9;
            const ushort* p = awbase + ((size_t)glo << 11) + (tt - (glo << 9));
            float s = bf16f(p[0]) + bf16f(p[1536]) + bf16f(p[3072]) + bf16f(p[4608]);
            v = s * 0.25f;
        } else if (tt >= 0 && tt < TARLEN) {
            int ghi = min(511, tt >> 9);
            int glo = max(0, (tt - 1536) >> 9);
            float s = 0.f;
            for (int g = glo; g <= ghi; ++g) {
                int n = tt - (g << 9);
                s += bf16f(awbase[((size_t)g << 11) + n]);
            }
            v = s / (float)(ghi - glo + 1);
        }
        tile[i] = v;
    }
    if (threadIdx.x < 65) {
        float k = 0.f;
#pragma unroll
        for (int c = 0; c < 5; ++c) k += ppw[c * 65 + threadIdx.x];
        Ksh[threadIdx.x] = k;
    }
    __syncthreads();
    float y = ppb[0];
#pragma unroll
    for (int j = 0; j < 65; ++j) y = fmaf(Ksh[j], tile[threadIdx.x + j], y);
    int t = t0 + threadIdx.x;
    out[(size_t)b * TARLEN + t] = y / (1.f + fabsf(y));
}

// ---------------- launch --------------------------------------------------
extern "C" void kernel_launch(void* const* d_in, const int* in_sizes, int n_in,
                              void* d_out, int out_size, void* d_ws, size_t ws_size,
                              hipStream_t stream) {
    const float* z    = (const float*)d_in[0];
    const float* w0   = (const float*)d_in[1];
    const float* b0   = (const float*)d_in[2];
    const float* g0   = (const float*)d_in[3];
    const float* be0  = (const float*)d_in[4];
    const float* w1   = (const float*)d_in[5];
    const float* b1   = (const float*)d_in[6];
    const float* g1   = (const float*)d_in[7];
    const float* be1  = (const float*)d_in[8];
    const float* w2   = (const float*)d_in[9];
    const float* b2   = (const float*)d_in[10];
    const float* g2   = (const float*)d_in[11];
    const float* be2  = (const float*)d_in[12];
    const float* w3   = (const float*)d_in[13];
    const float* b3   = (const float*)d_in[14];
    const float* ppw  = (const float*)d_in[15];
    const float* ppb  = (const float*)d_in[16];
    const float* noise= (const float*)d_in[17];
    float* out = (float*)d_out;
    float* ws = (float*)d_ws;

    // workspace (float offsets)
    ushort* h0b = (ushort*)ws;                    // 8192*512 bf16
    ushort* h1b = (ushort*)(ws + 2097152);        // 8192*512 bf16
    float* ps0  = ws + 4194304;                   // 64*512
    float* pq0  = ps0 + 32768;
    float* ps1  = pq0 + 32768;
    float* pq1  = ps1 + 32768;
    float* base = pq1 + 32768;
    ushort* Bt0 = (ushort*)base;                  // 512*128 bf16
    ushort* Bt1 = (ushort*)(base + 32768);        // 512*512 bf16
    ushort* Bt2 = (ushort*)(base + 163840);       // 512*512 bf16
    ushort* Bt3 = (ushort*)(base + 294912);       // 1152*512 bf16
    ushort* fcsb= (ushort*)(base + 589824);       // 8192*1040 bf16
    ushort* awb = (ushort*)(base + 4849664);      // 8192*2048 bf16
    ushort* A   = (ushort*)(base + 13238272);     // 8192*128 bf16 (z cast)
    ushort* h2b = h0b;  // h0 dead after gemm1 consumed it

    dim3 blk(256);
    dim3 gblk(512);
    // input prep (4 weight transposes + z cast) in one launch
    prep_inputs<<<dim3(16, 36, 5), blk, 0, stream>>>(
        w0, w1, w2, w3, z, Bt0, Bt1, Bt2, Bt3, A);
    // layer 0: h0 = z @ w0 + b0 (+ stats -> S0); K=128
    gemm8<<<dim3(4, 64), gblk, 0, stream>>>(A, Bt0, b0, h0b, 128, ps0, pq0);
    // layer 1: fused BN(S0)+lrelu on A, gemm, stats -> S1
    gemm8n<0><<<dim3(4, 64), gblk, 0, stream>>>(
        h0b, Bt1, b1, ps0, pq0, g0, be0, h1b, 512, 512, 512, ps1, pq1);
    // layer 2: fused BN(S1), stats -> S0
    gemm8n<0><<<dim3(4, 64), gblk, 0, stream>>>(
        h1b, Bt2, b2, ps1, pq1, g1, be1, h2b, 512, 512, 512, ps0, pq0);
    // layer 3: fused BN(S0), mod_sigmoid -> fcsb [8192][1040], 1025 valid
    gemm8n<1><<<dim3(9, 64), gblk, 0, stream>>>(
        h2b, Bt3, b3, ps0, pq0, g2, be2, fcsb, 512, 1025, 1040, nullptr, nullptr);
    // spectral filtering + window (fused), bf16 in/out
    fft_filter_kernel<<<dim3(8192), blk, 0, stream>>>(noise, fcsb, awb);
    // fused OLA + post conv + softsign
    ola_ppconv_kernel<<<dim3(1030, 16), blk, 0, stream>>>(awb, ppw, ppb, out);
    (void)in_sizes; (void)n_in; (void)out_size; (void)ws_size;
}